// Round 1
// baseline (1665.188 us; speedup 1.0000x reference)
//
#include <hip/hip_runtime.h>
#include <math.h>

#define NN 4096
#define QQ 1024
#define LDA 1032              // padded leading dim (16B-aligned rows)
#define AF (1025 * 1032)      // floats occupied by bordered matrix A (1025 rows)

// ---------------- stats: r = yt-yp; s[q] += r; c[q] += 1; rr = sum r^2 ----------------
__global__ void k_stats(const float* __restrict__ yt, const float* __restrict__ yp,
                        const int* __restrict__ idx, float* __restrict__ s,
                        int* __restrict__ c, float* __restrict__ scal) {
    int i = blockIdx.x * 256 + threadIdx.x;
    float r = yt[i] - yp[i];
    int q = idx[i];
    atomicAdd(&s[q], r);
    atomicAdd(&c[q], 1);
    float v = r * r;
    for (int o = 32; o > 0; o >>= 1) v += __shfl_down(v, o, 64);
    __shared__ float red[4];
    int lane = threadIdx.x & 63, wid = threadIdx.x >> 6;
    if (lane == 0) red[wid] = v;
    __syncthreads();
    if (threadIdx.x == 0) atomicAdd(&scal[0], red[0] + red[1] + red[2] + red[3]);
}

// ---------------- matvec: t = D s ; w = sqrt(c)*t ; sqc ; st = s.t ----------------
__global__ void k_matvec(const float* __restrict__ dist, const float* __restrict__ s,
                         const int* __restrict__ c, float* __restrict__ t,
                         float* __restrict__ w, float* __restrict__ sqc,
                         float* __restrict__ scal, const float* __restrict__ sbs) {
    int i = blockIdx.x;
    float sb0 = sbs[0];
    float inv2 = 1.0f / (2.0f * sbs[1]);
    const float* dr = dist + (size_t)i * QQ;
    float acc = 0.f;
    for (int j = threadIdx.x; j < QQ; j += 256)
        acc += __expf(-dr[j] * inv2) * s[j];
    for (int o = 32; o > 0; o >>= 1) acc += __shfl_down(acc, o, 64);
    __shared__ float red[4];
    int lane = threadIdx.x & 63, wid = threadIdx.x >> 6;
    if (lane == 0) red[wid] = acc;
    __syncthreads();
    if (threadIdx.x == 0) {
        float tot = (red[0] + red[1] + red[2] + red[3]) * sb0;
        t[i] = tot;
        float sq = sqrtf((float)c[i]);
        sqc[i] = sq;
        w[i] = sq * tot;
        atomicAdd(&scal[1], s[i] * tot);
    }
}

// ---------------- build bordered S: A[i][j] = I + inv_se*sqc_i*sqc_j*D_ij; row QQ = w ----------------
__global__ void k_build(const float* __restrict__ dist, const float* __restrict__ sqc,
                        const float* __restrict__ w, float* __restrict__ A,
                        const float* __restrict__ se_p, const float* __restrict__ sbs) {
    int i = blockIdx.x;  // 0..1024
    if (i == QQ) {
        for (int j = threadIdx.x; j < QQ; j += 256) A[(size_t)QQ * LDA + j] = w[j];
        return;
    }
    float sb0 = sbs[0];
    float inv2 = 1.0f / (2.0f * sbs[1]);
    float inv_se = 1.0f / se_p[0];
    float qi = sqc[i] * inv_se * sb0;
    const float* dr = dist + (size_t)i * QQ;
    float* ar = A + (size_t)i * LDA;
    for (int j = threadIdx.x; j < QQ; j += 256)
        ar[j] = ((i == j) ? 1.0f : 0.0f) + qi * sqc[j] * __expf(-dr[j] * inv2);
}

// ---------------- potrf of 64x64 diag block (single block, 256 threads) ----------------
__global__ void k_potrf(float* __restrict__ A, int p) {
    __shared__ float T[64][65];
    __shared__ float diag_s[64];
    int t = threadIdx.x;
    int j = t & 63, q = t >> 6;
    float* base = A + (size_t)(p * 64) * (LDA + 1);
    for (int i = q; i < 64; i += 4) T[i][j] = base[(size_t)i * LDA + j];
    __syncthreads();
    for (int k = 0; k < 64; ++k) {
        if (j == k) {
            float dk = T[k][k];      // never written in this phase (diag kept in diag_s)
            float sd = sqrtf(dk);
            float r = 1.0f / sd;
            if (q == 0) diag_s[k] = sd;
            for (int i = k + 1 + q; i < 64; i += 4) T[i][k] *= r;
        }
        __syncthreads();
        if (j > k) {
            float ljk = T[j][k];
            for (int i = j + q; i < 64; i += 4)
                T[i][j] = fmaf(-T[i][k], ljk, T[i][j]);
        }
        __syncthreads();
    }
    for (int i = q; i < 64; i += 4)
        if (i >= j) base[(size_t)i * LDA + j] = (i == j) ? diag_s[j] : T[i][j];
}

// ---------------- trsm: rows below panel (incl. bordered w-row): X * Lpp^T = A_panel ----------------
__global__ void k_trsm(float* __restrict__ A, int p) {
    __shared__ float Lb[64][65];
    __shared__ float dinv[64];
    int t = threadIdx.x;  // 64 threads
    const float* db = A + (size_t)(p * 64) * (LDA + 1);
    for (int i = 0; i < 64; ++i) Lb[i][t] = db[(size_t)i * LDA + t];
    dinv[t] = 1.0f / Lb[t][t];
    __syncthreads();
    int r = (p + 1) * 64 + blockIdx.x * 64 + t;
    if (r <= QQ) {
        float* ar = A + (size_t)r * LDA + p * 64;
        float x[64];
#pragma unroll
        for (int jj = 0; jj < 16; ++jj) {
            float4 v = ((const float4*)ar)[jj];
            x[4 * jj] = v.x; x[4 * jj + 1] = v.y; x[4 * jj + 2] = v.z; x[4 * jj + 3] = v.w;
        }
#pragma unroll
        for (int jj = 0; jj < 64; ++jj) {
            float a0 = x[jj], a1 = 0.f;
#pragma unroll
            for (int m = 0; m + 1 < jj; m += 2) {
                a0 = fmaf(-Lb[jj][m], x[m], a0);
                a1 = fmaf(-Lb[jj][m + 1], x[m + 1], a1);
            }
            if (jj & 1) a0 = fmaf(-Lb[jj][jj - 1], x[jj - 1], a0);
            x[jj] = (a0 + a1) * dinv[jj];
        }
#pragma unroll
        for (int jj = 0; jj < 16; ++jj)
            ((float4*)ar)[jj] = make_float4(x[4 * jj], x[4 * jj + 1], x[4 * jj + 2], x[4 * jj + 3]);
    }
}

// ---------------- syrk: trailing update A -= P * P^T (lower tiles only) ----------------
__global__ void k_syrk(float* __restrict__ A, int p) {
    int t0 = (p + 1) * 64;
    int r0 = t0 + blockIdx.y * 32;
    int c0 = t0 + blockIdx.x * 32;
    if (c0 > r0 + 31) return;  // uniform: tile entirely above diagonal
    __shared__ float Pr[32][65];
    __shared__ float Pc[32][65];
    int t = threadIdx.x;  // 256
    int pc0 = p * 64;
    for (int idx2 = t; idx2 < 2048; idx2 += 256) {
        int i = idx2 >> 6, k = idx2 & 63;
        int rr = r0 + i;
        Pr[i][k] = (rr <= QQ) ? A[(size_t)rr * LDA + pc0 + k] : 0.f;
        int cc = c0 + i;
        Pc[i][k] = (cc < QQ) ? A[(size_t)cc * LDA + pc0 + k] : 0.f;
    }
    __syncthreads();
    int tx = t & 31, ty = t >> 5;  // ty 0..7
    float acc[4] = {0.f, 0.f, 0.f, 0.f};
#pragma unroll 4
    for (int k = 0; k < 64; ++k) {
        float b = Pc[tx][k];
#pragma unroll
        for (int ii = 0; ii < 4; ++ii)
            acc[ii] = fmaf(Pr[ty + 8 * ii][k], b, acc[ii]);
    }
#pragma unroll
    for (int ii = 0; ii < 4; ++ii) {
        int rr = r0 + ty + 8 * ii, cc = c0 + tx;
        if (rr <= QQ && cc < QQ)
            A[(size_t)rr * LDA + cc] -= acc[ii];
    }
}

// ---------------- finalize: logdet from diag, yy from bordered row, combine ----------------
__global__ void k_final(const float* __restrict__ A, const float* __restrict__ scal,
                        const float* __restrict__ se_p, float* __restrict__ out) {
    int i = threadIdx.x;  // 1024
    float v1 = 2.0f * __logf(A[(size_t)i * LDA + i]);
    float yv = A[(size_t)QQ * LDA + i];
    float v2 = yv * yv;
    for (int o = 32; o > 0; o >>= 1) {
        v1 += __shfl_down(v1, o, 64);
        v2 += __shfl_down(v2, o, 64);
    }
    __shared__ float r1[16], r2[16];
    int lane = i & 63, wid = i >> 6;
    if (lane == 0) { r1[wid] = v1; r2[wid] = v2; }
    __syncthreads();
    if (i == 0) {
        float ld = 0.f, yy = 0.f;
        for (int k = 0; k < 16; ++k) { ld += r1[k]; yy += r2[k]; }
        float se = se_p[0], inv = 1.0f / se;
        float rr = scal[0], st = scal[1];
        float quad = rr * inv - inv * inv * (st - inv * yy);
        float logdetV = (float)NN * __logf(se) + ld;
        out[0] = 0.5f * (float)NN * 1.8378770664093453f + 0.5f * logdetV + 0.5f * quad;
    }
}

extern "C" void kernel_launch(void* const* d_in, const int* in_sizes, int n_in,
                              void* d_out, int out_size, void* d_ws, size_t ws_size,
                              hipStream_t stream) {
    const float* yt   = (const float*)d_in[0];
    const float* yp   = (const float*)d_in[1];
    const int*   idx  = (const int*)d_in[2];
    const float* dist = (const float*)d_in[3];
    const float* se   = (const float*)d_in[4];
    const float* sbs  = (const float*)d_in[5];
    float* out = (float*)d_out;

    float* W    = (float*)d_ws;
    float* A    = W;                      // 1025 x LDA
    int*   c    = (int*)(W + AF);         // 1024
    float* s    = W + AF + 1024;          // 1024
    float* scal = W + AF + 2048;          // rr, st
    float* t    = scal + 2;               // 1024
    float* w    = t + 1024;               // 1024
    float* sqc  = w + 1024;               // 1024

    // zero accumulators: c(1024 int) + s(1024 f) + scal(2 f), contiguous
    hipMemsetAsync(c, 0, (1024 + 1024 + 2) * sizeof(float), stream);

    k_stats<<<dim3(NN / 256), dim3(256), 0, stream>>>(yt, yp, idx, s, c, scal);
    k_matvec<<<dim3(QQ), dim3(256), 0, stream>>>(dist, s, c, t, w, sqc, scal, sbs);
    k_build<<<dim3(QQ + 1), dim3(256), 0, stream>>>(dist, sqc, w, A, se, sbs);

    for (int p = 0; p < 16; ++p) {
        k_potrf<<<dim3(1), dim3(256), 0, stream>>>(A, p);
        int rows = (QQ + 1) - (p + 1) * 64;
        k_trsm<<<dim3((rows + 63) / 64), dim3(64), 0, stream>>>(A, p);
        int cols = QQ - (p + 1) * 64;
        if (cols > 0) {
            dim3 g((cols + 31) / 32, (rows + 31) / 32);
            k_syrk<<<g, dim3(256), 0, stream>>>(A, p);
        }
    }
    k_final<<<dim3(1), dim3(1024), 0, stream>>>(A, scal, se, out);
}

// Round 2
// 848.675 us; speedup vs baseline: 1.9621x; 1.9621x over previous
//
#include <hip/hip_runtime.h>
#include <math.h>

#define NN 4096
#define QQ 1024
#define LDA 1032              // padded leading dim (16B-aligned rows)
#define AF (1025 * 1032)      // floats occupied by bordered matrix A (1025 rows)

// ---------------- stats: r = yt-yp; s[q] += r; c[q] += 1; rr = sum r^2 ----------------
__global__ void k_stats(const float* __restrict__ yt, const float* __restrict__ yp,
                        const int* __restrict__ idx, float* __restrict__ s,
                        int* __restrict__ c, float* __restrict__ scal) {
    int i = blockIdx.x * 256 + threadIdx.x;
    float r = yt[i] - yp[i];
    int q = idx[i];
    atomicAdd(&s[q], r);
    atomicAdd(&c[q], 1);
    float v = r * r;
    for (int o = 32; o > 0; o >>= 1) v += __shfl_down(v, o, 64);
    __shared__ float red[4];
    int lane = threadIdx.x & 63, wid = threadIdx.x >> 6;
    if (lane == 0) red[wid] = v;
    __syncthreads();
    if (threadIdx.x == 0) atomicAdd(&scal[0], red[0] + red[1] + red[2] + red[3]);
}

// ---------------- matvec: t = D s ; w = sqrt(c)*t ; sqc ; st = s.t ----------------
__global__ void k_matvec(const float* __restrict__ dist, const float* __restrict__ s,
                         const int* __restrict__ c, float* __restrict__ t,
                         float* __restrict__ w, float* __restrict__ sqc,
                         float* __restrict__ scal, const float* __restrict__ sbs) {
    int i = blockIdx.x;
    float sb0 = sbs[0];
    float inv2 = 1.0f / (2.0f * sbs[1]);
    const float* dr = dist + (size_t)i * QQ;
    float acc = 0.f;
    for (int j = threadIdx.x; j < QQ; j += 256)
        acc += __expf(-dr[j] * inv2) * s[j];
    for (int o = 32; o > 0; o >>= 1) acc += __shfl_down(acc, o, 64);
    __shared__ float red[4];
    int lane = threadIdx.x & 63, wid = threadIdx.x >> 6;
    if (lane == 0) red[wid] = acc;
    __syncthreads();
    if (threadIdx.x == 0) {
        float tot = (red[0] + red[1] + red[2] + red[3]) * sb0;
        t[i] = tot;
        float sq = sqrtf((float)c[i]);
        sqc[i] = sq;
        w[i] = sq * tot;
        atomicAdd(&scal[1], s[i] * tot);
    }
}

// ---------------- build bordered S: A[i][j] = I + inv_se*sqc_i*sqc_j*D_ij; row QQ = w ----------------
__global__ void k_build(const float* __restrict__ dist, const float* __restrict__ sqc,
                        const float* __restrict__ w, float* __restrict__ A,
                        const float* __restrict__ se_p, const float* __restrict__ sbs) {
    int i = blockIdx.x;  // 0..1024
    if (i == QQ) {
        for (int j = threadIdx.x; j < QQ; j += 256) A[(size_t)QQ * LDA + j] = w[j];
        return;
    }
    float sb0 = sbs[0];
    float inv2 = 1.0f / (2.0f * sbs[1]);
    float inv_se = 1.0f / se_p[0];
    float qi = sqc[i] * inv_se * sb0;
    const float* dr = dist + (size_t)i * QQ;
    float* ar = A + (size_t)i * LDA;
    for (int j = threadIdx.x; j < QQ; j += 256)
        ar[j] = ((i == j) ? 1.0f : 0.0f) + qi * sqc[j] * __expf(-dr[j] * inv2);
}

// ---------------- potrf of 64x64 diag block: 64 threads, register-resident rows ----------------
// Thread j holds row j of the block in 64 VGPRs. Per step k:
//   - pivot broadcast via __shfl (no LDS round-trip)
//   - column k published once to double-buffered LDS, re-read as float4 (broadcast)
//   - rank-1 update entirely in registers, fully unrolled
// One barrier per step; single wave so it is near-free. Above-diagonal register
// values become garbage but are never consumed downstream (trsm reads lower+diag).
__global__ __launch_bounds__(64) void k_potrf(float* __restrict__ A, int p) {
    __shared__ float colL[2][64];
    int j = threadIdx.x;
    float* row = A + (size_t)(p * 64 + j) * LDA + p * 64;
    float x[64];
#pragma unroll
    for (int m4 = 0; m4 < 16; ++m4) {
        float4 v = ((const float4*)row)[m4];
        x[4 * m4 + 0] = v.x; x[4 * m4 + 1] = v.y;
        x[4 * m4 + 2] = v.z; x[4 * m4 + 3] = v.w;
    }
#pragma unroll
    for (int k = 0; k < 64; ++k) {
        float diag = __shfl(x[k], k, 64);
        float s_ = sqrtf(diag);
        float inv = 1.0f / s_;
        float l = (j == k) ? s_ : x[k] * inv;   // lane j>k: L[j][k]; lane k: L[k][k]
        if (j >= k) x[k] = l;
        colL[k & 1][j] = l;
        __syncthreads();
        float cl[64];
#pragma unroll
        for (int m4 = 0; m4 < 16; ++m4) {
            float4 v = ((const float4*)(&colL[k & 1][0]))[m4];
            cl[4 * m4 + 0] = v.x; cl[4 * m4 + 1] = v.y;
            cl[4 * m4 + 2] = v.z; cl[4 * m4 + 3] = v.w;
        }
#pragma unroll
        for (int m = k + 1; m < 64; ++m)
            x[m] = fmaf(-l, cl[m], x[m]);       // lanes j<=k only touch m>j garbage
    }
#pragma unroll
    for (int m4 = 0; m4 < 16; ++m4)
        ((float4*)row)[m4] = make_float4(x[4 * m4], x[4 * m4 + 1],
                                         x[4 * m4 + 2], x[4 * m4 + 3]);
}

// ---------------- trsm: rows below panel (incl. bordered w-row): X * Lpp^T = A_panel ----------------
__global__ void k_trsm(float* __restrict__ A, int p) {
    __shared__ float Lb[64][65];
    __shared__ float dinv[64];
    int t = threadIdx.x;  // 64 threads
    const float* db = A + (size_t)(p * 64) * (LDA + 1);
    for (int i = 0; i < 64; ++i) Lb[i][t] = db[(size_t)i * LDA + t];
    dinv[t] = 1.0f / Lb[t][t];
    __syncthreads();
    int r = (p + 1) * 64 + blockIdx.x * 64 + t;
    if (r <= QQ) {
        float* ar = A + (size_t)r * LDA + p * 64;
        float x[64];
#pragma unroll
        for (int jj = 0; jj < 16; ++jj) {
            float4 v = ((const float4*)ar)[jj];
            x[4 * jj] = v.x; x[4 * jj + 1] = v.y; x[4 * jj + 2] = v.z; x[4 * jj + 3] = v.w;
        }
#pragma unroll
        for (int jj = 0; jj < 64; ++jj) {
            float a0 = x[jj], a1 = 0.f;
#pragma unroll
            for (int m = 0; m + 1 < jj; m += 2) {
                a0 = fmaf(-Lb[jj][m], x[m], a0);
                a1 = fmaf(-Lb[jj][m + 1], x[m + 1], a1);
            }
            if (jj & 1) a0 = fmaf(-Lb[jj][jj - 1], x[jj - 1], a0);
            x[jj] = (a0 + a1) * dinv[jj];
        }
#pragma unroll
        for (int jj = 0; jj < 16; ++jj)
            ((float4*)ar)[jj] = make_float4(x[4 * jj], x[4 * jj + 1], x[4 * jj + 2], x[4 * jj + 3]);
    }
}

// ---------------- syrk: trailing update A -= P * P^T (lower tiles only) ----------------
__global__ void k_syrk(float* __restrict__ A, int p) {
    int t0 = (p + 1) * 64;
    int r0 = t0 + blockIdx.y * 32;
    int c0 = t0 + blockIdx.x * 32;
    if (c0 > r0 + 31) return;  // uniform: tile entirely above diagonal
    __shared__ float Pr[32][65];
    __shared__ float Pc[32][65];
    int t = threadIdx.x;  // 256
    int pc0 = p * 64;
    for (int idx2 = t; idx2 < 2048; idx2 += 256) {
        int i = idx2 >> 6, k = idx2 & 63;
        int rr = r0 + i;
        Pr[i][k] = (rr <= QQ) ? A[(size_t)rr * LDA + pc0 + k] : 0.f;
        int cc = c0 + i;
        Pc[i][k] = (cc < QQ) ? A[(size_t)cc * LDA + pc0 + k] : 0.f;
    }
    __syncthreads();
    int tx = t & 31, ty = t >> 5;  // ty 0..7
    float acc[4] = {0.f, 0.f, 0.f, 0.f};
#pragma unroll 4
    for (int k = 0; k < 64; ++k) {
        float b = Pc[tx][k];
#pragma unroll
        for (int ii = 0; ii < 4; ++ii)
            acc[ii] = fmaf(Pr[ty + 8 * ii][k], b, acc[ii]);
    }
#pragma unroll
    for (int ii = 0; ii < 4; ++ii) {
        int rr = r0 + ty + 8 * ii, cc = c0 + tx;
        if (rr <= QQ && cc < QQ)
            A[(size_t)rr * LDA + cc] -= acc[ii];
    }
}

// ---------------- finalize: logdet from diag, yy from bordered row, combine ----------------
__global__ void k_final(const float* __restrict__ A, const float* __restrict__ scal,
                        const float* __restrict__ se_p, float* __restrict__ out) {
    int i = threadIdx.x;  // 1024
    float v1 = 2.0f * __logf(A[(size_t)i * LDA + i]);
    float yv = A[(size_t)QQ * LDA + i];
    float v2 = yv * yv;
    for (int o = 32; o > 0; o >>= 1) {
        v1 += __shfl_down(v1, o, 64);
        v2 += __shfl_down(v2, o, 64);
    }
    __shared__ float r1[16], r2[16];
    int lane = i & 63, wid = i >> 6;
    if (lane == 0) { r1[wid] = v1; r2[wid] = v2; }
    __syncthreads();
    if (i == 0) {
        float ld = 0.f, yy = 0.f;
        for (int k = 0; k < 16; ++k) { ld += r1[k]; yy += r2[k]; }
        float se = se_p[0], inv = 1.0f / se;
        float rr = scal[0], st = scal[1];
        float quad = rr * inv - inv * inv * (st - inv * yy);
        float logdetV = (float)NN * __logf(se) + ld;
        out[0] = 0.5f * (float)NN * 1.8378770664093453f + 0.5f * logdetV + 0.5f * quad;
    }
}

extern "C" void kernel_launch(void* const* d_in, const int* in_sizes, int n_in,
                              void* d_out, int out_size, void* d_ws, size_t ws_size,
                              hipStream_t stream) {
    const float* yt   = (const float*)d_in[0];
    const float* yp   = (const float*)d_in[1];
    const int*   idx  = (const int*)d_in[2];
    const float* dist = (const float*)d_in[3];
    const float* se   = (const float*)d_in[4];
    const float* sbs  = (const float*)d_in[5];
    float* out = (float*)d_out;

    float* W    = (float*)d_ws;
    float* A    = W;                      // 1025 x LDA
    int*   c    = (int*)(W + AF);         // 1024
    float* s    = W + AF + 1024;          // 1024
    float* scal = W + AF + 2048;          // rr, st
    float* t    = scal + 2;               // 1024
    float* w    = t + 1024;               // 1024
    float* sqc  = w + 1024;               // 1024

    // zero accumulators: c(1024 int) + s(1024 f) + scal(2 f), contiguous
    hipMemsetAsync(c, 0, (1024 + 1024 + 2) * sizeof(float), stream);

    k_stats<<<dim3(NN / 256), dim3(256), 0, stream>>>(yt, yp, idx, s, c, scal);
    k_matvec<<<dim3(QQ), dim3(256), 0, stream>>>(dist, s, c, t, w, sqc, scal, sbs);
    k_build<<<dim3(QQ + 1), dim3(256), 0, stream>>>(dist, sqc, w, A, se, sbs);

    for (int p = 0; p < 16; ++p) {
        k_potrf<<<dim3(1), dim3(64), 0, stream>>>(A, p);
        int rows = (QQ + 1) - (p + 1) * 64;
        k_trsm<<<dim3((rows + 63) / 64), dim3(64), 0, stream>>>(A, p);
        int cols = QQ - (p + 1) * 64;
        if (cols > 0) {
            dim3 g((cols + 31) / 32, (rows + 31) / 32);
            k_syrk<<<g, dim3(256), 0, stream>>>(A, p);
        }
    }
    k_final<<<dim3(1), dim3(1024), 0, stream>>>(A, scal, se, out);
}